// Round 1
// baseline (5517.599 us; speedup 1.0000x reference)
//
#include <hip/hip_runtime.h>

#define N_NODES 100000
#define N_EDGES 3200000
#define D 128

// ---------------------------------------------------------------------------
// Kernel A: support = x @ W + bias   (M x 128) @ (128 x 128), fp32 vector ALU
// Block = 256 threads, processes 32 rows. W (64KB) + x-chunk (16KB) in LDS.
// Each thread computes a 4x4 micro-tile: 2 FMA per LDS dword read, all reads
// are ds_read_b128; x reads broadcast within half-wave (same address).
// ---------------------------------------------------------------------------
__global__ __launch_bounds__(256) void gcn_gemm_kernel(
    const float* __restrict__ x, const float* __restrict__ W,
    const float* __restrict__ bias, float* __restrict__ support, int M) {
  __shared__ float Wl[D * D];    // 64 KB
  __shared__ float Xl[32 * D];   // 16 KB
  const int t = threadIdx.x;

  // Stage W: 16384 floats = 4096 float4, 256 threads -> 16 each
  for (int i = t * 4; i < D * D; i += 256 * 4) {
    *(float4*)&Wl[i] = *(const float4*)&W[i];
  }
  // Stage x chunk: 32 rows x 128 = 4096 floats
  const int row0 = blockIdx.x * 32;
  for (int i = t * 4; i < 32 * D; i += 256 * 4) {
    const int r = row0 + i / D;
    float4 v = make_float4(0.f, 0.f, 0.f, 0.f);
    if (r < M) v = *(const float4*)&x[(size_t)r * D + (i % D)];
    *(float4*)&Xl[i] = v;
  }
  __syncthreads();

  const int rt = t >> 5;          // 0..7  -> row tile
  const int ct = t & 31;          // 0..31 -> col tile
  const int rbase = rt * 4;
  const int cbase = ct * 4;

  float acc[4][4] = {};
  for (int k = 0; k < D; k += 4) {
    float4 xv[4];
#pragma unroll
    for (int i = 0; i < 4; i++) xv[i] = *(float4*)&Xl[(rbase + i) * D + k];
    float4 wv[4];
#pragma unroll
    for (int kk = 0; kk < 4; kk++) wv[kk] = *(float4*)&Wl[(k + kk) * D + cbase];
#pragma unroll
    for (int i = 0; i < 4; i++) {
      const float* xs = (const float*)&xv[i];
#pragma unroll
      for (int kk = 0; kk < 4; kk++) {
        acc[i][0] += xs[kk] * wv[kk].x;
        acc[i][1] += xs[kk] * wv[kk].y;
        acc[i][2] += xs[kk] * wv[kk].z;
        acc[i][3] += xs[kk] * wv[kk].w;
      }
    }
  }

  const float4 bv = *(const float4*)&bias[cbase];
#pragma unroll
  for (int i = 0; i < 4; i++) {
    const int r = row0 + rbase + i;
    if (r < M) {
      float4 o = make_float4(acc[i][0] + bv.x, acc[i][1] + bv.y,
                             acc[i][2] + bv.z, acc[i][3] + bv.w);
      *(float4*)&support[(size_t)r * D + cbase] = o;
    }
  }
}

// ---------------------------------------------------------------------------
// Kernel B: out[row] += val * support[col] per edge, via fp32 HW atomics.
// Half-wave (32 threads) per edge, float4 per thread: coalesced 512B gather
// and coalesced atomic scatter.
// ---------------------------------------------------------------------------
__global__ __launch_bounds__(256) void gcn_spmm_kernel(
    const float* __restrict__ support, const float* __restrict__ edge_val,
    const int* __restrict__ edge_row, const int* __restrict__ edge_col,
    float* __restrict__ out) {
  const long long tid = (long long)blockIdx.x * blockDim.x + threadIdx.x;
  const int e = (int)(tid >> 5);
  if (e >= N_EDGES) return;
  const int j = ((int)tid & 31) * 4;

  const int col = edge_col[e];
  const int row = edge_row[e];
  const float val = edge_val[e];

  const float4 s = *(const float4*)&support[(size_t)col * D + j];
  float* dst = &out[(size_t)row * D + j];
  unsafeAtomicAdd(dst + 0, s.x * val);
  unsafeAtomicAdd(dst + 1, s.y * val);
  unsafeAtomicAdd(dst + 2, s.z * val);
  unsafeAtomicAdd(dst + 3, s.w * val);
}

extern "C" void kernel_launch(void* const* d_in, const int* in_sizes, int n_in,
                              void* d_out, int out_size, void* d_ws,
                              size_t ws_size, hipStream_t stream) {
  const float* x        = (const float*)d_in[0];
  const float* edge_val = (const float*)d_in[1];
  const float* W        = (const float*)d_in[2];
  const float* bias     = (const float*)d_in[3];
  const int*   edge_row = (const int*)d_in[4];
  const int*   edge_col = (const int*)d_in[5];
  float* out = (float*)d_out;
  float* support = (float*)d_ws;  // 100000*128*4 = 51.2 MB scratch

  // d_out is poisoned to 0xAA before every timed launch -> zero it (atomics).
  hipMemsetAsync(d_out, 0, (size_t)out_size * sizeof(float), stream);

  // support = x @ W + bias
  const int gemm_blocks = (N_NODES + 31) / 32;
  gcn_gemm_kernel<<<gemm_blocks, 256, 0, stream>>>(x, W, bias, support, N_NODES);

  // out = scatter-add(edge_val * support[edge_col]) into edge_row
  const long long spmm_threads = (long long)N_EDGES * 32;
  const int spmm_blocks = (int)((spmm_threads + 255) / 256);
  gcn_spmm_kernel<<<spmm_blocks, 256, 0, stream>>>(support, edge_val, edge_row,
                                                   edge_col, out);
}

// Round 2
// 727.838 us; speedup vs baseline: 7.5808x; 7.5808x over previous
//
#include <hip/hip_runtime.h>

#define N_NODES 100000
#define N_EDGES 3200000
#define D 128

#define SCAN_TILE 1024
#define NBLK ((N_NODES + SCAN_TILE - 1) / SCAN_TILE)   // 98

// ws layout (bytes)
#define SUPPORT_OFF 0
#define OFF_OFF     51200000ULL                 // 100000 ints (counts -> offsets -> ends)
#define BSUM_OFF    51600000ULL                 // 512 ints
#define RECS_OFF    51602048ULL                 // 3.2M int2 = 25.6 MB, 8B aligned
#define WS_NEED     (RECS_OFF + (size_t)N_EDGES * 8)

// ---------------------------------------------------------------------------
// Kernel A: support = x @ W + bias   (fp32 vector ALU)
// ---------------------------------------------------------------------------
__global__ __launch_bounds__(256) void gcn_gemm_kernel(
    const float* __restrict__ x, const float* __restrict__ W,
    const float* __restrict__ bias, float* __restrict__ support, int M) {
  __shared__ float Wl[D * D];
  __shared__ float Xl[32 * D];
  const int t = threadIdx.x;

  for (int i = t * 4; i < D * D; i += 256 * 4)
    *(float4*)&Wl[i] = *(const float4*)&W[i];
  const int row0 = blockIdx.x * 32;
  for (int i = t * 4; i < 32 * D; i += 256 * 4) {
    const int r = row0 + i / D;
    float4 v = make_float4(0.f, 0.f, 0.f, 0.f);
    if (r < M) v = *(const float4*)&x[(size_t)r * D + (i % D)];
    *(float4*)&Xl[i] = v;
  }
  __syncthreads();

  const int rbase = (t >> 5) * 4;
  const int cbase = (t & 31) * 4;
  float acc[4][4] = {};
  for (int k = 0; k < D; k += 4) {
    float4 xv[4];
#pragma unroll
    for (int i = 0; i < 4; i++) xv[i] = *(float4*)&Xl[(rbase + i) * D + k];
    float4 wv[4];
#pragma unroll
    for (int kk = 0; kk < 4; kk++) wv[kk] = *(float4*)&Wl[(k + kk) * D + cbase];
#pragma unroll
    for (int i = 0; i < 4; i++) {
      const float* xs = (const float*)&xv[i];
#pragma unroll
      for (int kk = 0; kk < 4; kk++) {
        acc[i][0] += xs[kk] * wv[kk].x;
        acc[i][1] += xs[kk] * wv[kk].y;
        acc[i][2] += xs[kk] * wv[kk].z;
        acc[i][3] += xs[kk] * wv[kk].w;
      }
    }
  }
  const float4 bv = *(const float4*)&bias[cbase];
#pragma unroll
  for (int i = 0; i < 4; i++) {
    const int r = row0 + rbase + i;
    if (r < M)
      *(float4*)&support[(size_t)r * D + cbase] =
          make_float4(acc[i][0] + bv.x, acc[i][1] + bv.y,
                      acc[i][2] + bv.z, acc[i][3] + bv.w);
  }
}

// ---------------------------------------------------------------------------
// CSR construction
// ---------------------------------------------------------------------------
__global__ __launch_bounds__(256) void hist_kernel(const int* __restrict__ erow,
                                                   int* __restrict__ cnt) {
  const int e = blockIdx.x * 256 + threadIdx.x;
  if (e < N_EDGES) atomicAdd(&cnt[erow[e]], 1);
}

__global__ __launch_bounds__(SCAN_TILE) void scan_reduce(
    const int* __restrict__ cnt, int* __restrict__ bsum) {
  __shared__ int s[SCAN_TILE];
  const int t = threadIdx.x;
  const int i = blockIdx.x * SCAN_TILE + t;
  s[t] = (i < N_NODES) ? cnt[i] : 0;
  __syncthreads();
  for (int off = SCAN_TILE / 2; off >= 1; off >>= 1) {
    if (t < off) s[t] += s[t + off];
    __syncthreads();
  }
  if (t == 0) bsum[blockIdx.x] = s[0];
}

__global__ __launch_bounds__(256) void scan_top(int* __restrict__ bsum) {
  __shared__ int buf[2][256];
  const int t = threadIdx.x;
  buf[0][t] = (t < NBLK) ? bsum[t] : 0;
  __syncthreads();
  int cur = 0;
  for (int off = 1; off < 256; off <<= 1) {
    const int nxt = cur ^ 1;
    buf[nxt][t] = buf[cur][t] + ((t >= off) ? buf[cur][t - off] : 0);
    __syncthreads();
    cur = nxt;
  }
  if (t < NBLK) bsum[t] = (t == 0) ? 0 : buf[cur][t - 1];  // exclusive
}

__global__ __launch_bounds__(SCAN_TILE) void scan_apply(
    int* __restrict__ cnt_off, const int* __restrict__ bsum) {
  __shared__ int buf[2][SCAN_TILE];
  const int t = threadIdx.x;
  const int i = blockIdx.x * SCAN_TILE + t;
  buf[0][t] = (i < N_NODES) ? cnt_off[i] : 0;
  __syncthreads();
  int cur = 0;
  for (int off = 1; off < SCAN_TILE; off <<= 1) {
    const int nxt = cur ^ 1;
    buf[nxt][t] = buf[cur][t] + ((t >= off) ? buf[cur][t - off] : 0);
    __syncthreads();
    cur = nxt;
  }
  if (i < N_NODES)
    cnt_off[i] = bsum[blockIdx.x] + ((t == 0) ? 0 : buf[cur][t - 1]);
}

// After this kernel, off[r] == end-offset of row r (start = off[r-1], off[-1]=0).
__global__ __launch_bounds__(256) void place_kernel(
    const int* __restrict__ erow, const int* __restrict__ ecol,
    const float* __restrict__ eval, int* __restrict__ off,
    int2* __restrict__ recs) {
  const int e = blockIdx.x * 256 + threadIdx.x;
  if (e >= N_EDGES) return;
  const int pos = atomicAdd(&off[erow[e]], 1);
  recs[pos] = make_int2(ecol[e], __float_as_int(eval[e]));
}

// ---------------------------------------------------------------------------
// Gather: one wave (64 lanes) per destination row; lane owns 2 columns.
// Metadata loaded coalesced (lane l reads record start+l), distributed via shfl.
// ---------------------------------------------------------------------------
__global__ __launch_bounds__(256) void gather_kernel(
    const float* __restrict__ support, const int* __restrict__ off,
    const int2* __restrict__ recs, float* __restrict__ out) {
  const int r = (blockIdx.x * 256 + threadIdx.x) >> 6;
  const int lane = threadIdx.x & 63;
  if (r >= N_NODES) return;
  const int start = (r == 0) ? 0 : off[r - 1];
  const int end = off[r];

  float2 acc = make_float2(0.f, 0.f);
  for (int base = start; base < end; base += 64) {
    int2 rec = make_int2(0, 0);
    if (base + lane < end) rec = recs[base + lane];
    const int n = min(64, end - base);
    for (int i = 0; i < n; i++) {
      const int col = __shfl(rec.x, i);
      const float val = __int_as_float(__shfl(rec.y, i));
      const float2 s = *(const float2*)&support[(size_t)col * D + lane * 2];
      acc.x += val * s.x;
      acc.y += val * s.y;
    }
  }
  *(float2*)&out[(size_t)r * D + lane * 2] = acc;
}

// Fallback (round-1 path) if ws is too small for CSR buffers.
__global__ __launch_bounds__(256) void gcn_spmm_atomic(
    const float* __restrict__ support, const float* __restrict__ edge_val,
    const int* __restrict__ edge_row, const int* __restrict__ edge_col,
    float* __restrict__ out) {
  const long long tid = (long long)blockIdx.x * blockDim.x + threadIdx.x;
  const int e = (int)(tid >> 5);
  if (e >= N_EDGES) return;
  const int j = ((int)tid & 31) * 4;
  const int col = edge_col[e];
  const int row = edge_row[e];
  const float val = edge_val[e];
  const float4 s = *(const float4*)&support[(size_t)col * D + j];
  float* dst = &out[(size_t)row * D + j];
  unsafeAtomicAdd(dst + 0, s.x * val);
  unsafeAtomicAdd(dst + 1, s.y * val);
  unsafeAtomicAdd(dst + 2, s.z * val);
  unsafeAtomicAdd(dst + 3, s.w * val);
}

extern "C" void kernel_launch(void* const* d_in, const int* in_sizes, int n_in,
                              void* d_out, int out_size, void* d_ws,
                              size_t ws_size, hipStream_t stream) {
  const float* x        = (const float*)d_in[0];
  const float* edge_val = (const float*)d_in[1];
  const float* W        = (const float*)d_in[2];
  const float* bias     = (const float*)d_in[3];
  const int*   edge_row = (const int*)d_in[4];
  const int*   edge_col = (const int*)d_in[5];
  float* out = (float*)d_out;

  char* ws = (char*)d_ws;
  float* support = (float*)(ws + SUPPORT_OFF);

  const int gemm_blocks = (N_NODES + 31) / 32;
  gcn_gemm_kernel<<<gemm_blocks, 256, 0, stream>>>(x, W, bias, support, N_NODES);

  const int eblocks = (N_EDGES + 255) / 256;

  if (ws_size >= WS_NEED) {
    int*  off  = (int*)(ws + OFF_OFF);
    int*  bsum = (int*)(ws + BSUM_OFF);
    int2* recs = (int2*)(ws + RECS_OFF);

    hipMemsetAsync(off, 0, N_NODES * sizeof(int), stream);
    hist_kernel<<<eblocks, 256, 0, stream>>>(edge_row, off);
    scan_reduce<<<NBLK, SCAN_TILE, 0, stream>>>(off, bsum);
    scan_top<<<1, 256, 0, stream>>>(bsum);
    scan_apply<<<NBLK, SCAN_TILE, 0, stream>>>(off, bsum);
    place_kernel<<<eblocks, 256, 0, stream>>>(edge_row, edge_col, edge_val,
                                              off, recs);
    const int gblocks = (N_NODES * 64 + 255) / 256;
    gather_kernel<<<gblocks, 256, 0, stream>>>(support, off, recs, out);
  } else {
    hipMemsetAsync(out, 0, (size_t)out_size * sizeof(float), stream);
    const long long spmm_threads = (long long)N_EDGES * 32;
    gcn_spmm_atomic<<<(int)((spmm_threads + 255) / 256), 256, 0, stream>>>(
        support, edge_val, edge_row, edge_col, out);
  }
}